// Round 12
// baseline (75.298 us; speedup 1.0000x reference)
//
#include <hip/hip_runtime.h>
#include <math.h>

#define THRESH_ 0.95f

typedef float nfloat4 __attribute__((ext_vector_type(4)));
typedef __attribute__((ext_vector_type(8))) short short8v;
typedef __attribute__((ext_vector_type(16))) float f32x16;

__device__ __forceinline__ unsigned short f2bf_rne(float x) {
    unsigned u = __float_as_uint(x);
    u += 0x7fffu + ((u >> 16) & 1u);
    return (unsigned short)(u >> 16);
}

// Fused kernel, 2 blocks per batch row (grid 512) so 2 blocks co-reside per CU:
// one block's compute overlaps the other's store drain. Block = (b = bid>>1,
// h = bid&1) handles segments [h*64, h*64+64) of row b.
__global__ __launch_bounds__(1024, 8) void k12_fused(const float* __restrict__ X,
                                                     const float* __restrict__ vocab,
                                                     const float* __restrict__ word_emb,
                                                     const float* __restrict__ haar_emb,
                                                     const float* __restrict__ pos_emb,
                                                     float* __restrict__ out) {
    __shared__ float4  wcl4[2048];    // fp32 centered vocab (32 KB)
    __shared__ short8v wcb_lds[1024]; // bf16 vocab (16 KB)
    __shared__ float   wsl[1024];     // word stds (4 KB)
    __shared__ float   xrow[1024];    // full X row (4 KB)
    __shared__ float   segf[512];     // fp32 centered segments [64][8]
    __shared__ short8v segb[64];      // bf16 segments
    __shared__ float   sstd_l[64];
    __shared__ float   thr_l[64];     // 7.52f * sstd
    __shared__ float   stb[512];      // [8 chunks][64 segs]
    __shared__ int     sti[512];
    __shared__ float   stm[512];
    __shared__ float   tree[254];
    __shared__ float   hc_lds[512];   // [64][8]
    __shared__ int     idx_lds[64];

    int t = threadIdx.x;
    int bid = blockIdx.x;
    int b = bid >> 1;
    int h = bid & 1;

    // ---- staging: X row + per-word vocab stats (identical arithmetic) ----
    xrow[t] = X[b * 1024 + t];
    {
        const float4* v4 = (const float4*)vocab + t * 2;
        float4 a = v4[0], bb = v4[1];
        float w[8] = {a.x, a.y, a.z, a.w, bb.x, bb.y, bb.z, bb.w};
        float s = 0.f;
#pragma unroll
        for (int c = 0; c < 8; c++) s += w[c];
        float mean = s * 0.125f;
        float ss = 0.f;
        float wcv[8];
#pragma unroll
        for (int c = 0; c < 8; c++) { wcv[c] = w[c] - mean; ss += wcv[c] * wcv[c]; }
        float sd = sqrtf(ss * 0.125f);
        float4 o0 = {wcv[0], wcv[1], wcv[2], wcv[3]};
        float4 o1 = {wcv[4], wcv[5], wcv[6], wcv[7]};
        wcl4[t * 2] = o0;
        wcl4[t * 2 + 1] = o1;
        wsl[t] = sd;
        union { uint4 q; unsigned short u[8]; } pk;
#pragma unroll
        for (int c = 0; c < 8; c++) pk.u[c] = f2bf_rne(wcv[c]);
        ((uint4*)wcb_lds)[t] = pk.q;
    }
    if (t < 512) { stb[t] = -INFINITY; sti[t] = -1; stm[t] = 0.f; }
    __syncthreads();

    // ---- segment sums (all 128, for haar tree) + stats for our 64 segments ----
    if (t < 128) {
        float seg[8];
#pragma unroll
        for (int c = 0; c < 8; c++) seg[c] = xrow[t * 8 + c];
        float sum = 0.f;
#pragma unroll
        for (int c = 0; c < 8; c++) sum += seg[c];
        tree[t] = sum;
        int local = t - h * 64;
        if (local >= 0 && local < 64) {
            float mean = sum * 0.125f;
            float segc[8];
            float ss = 0.f;
#pragma unroll
            for (int c = 0; c < 8; c++) { segc[c] = seg[c] - mean; ss += segc[c] * segc[c]; }
            float sstd = sqrtf(ss * 0.125f);
            union { short8v v; unsigned short u[8]; } pk;
#pragma unroll
            for (int c = 0; c < 8; c++) { segf[local * 8 + c] = segc[c]; pk.u[c] = f2bf_rne(segc[c]); }
            segb[local] = pk.v;
            sstd_l[local] = sstd;
            thr_l[local] = 7.52f * sstd;
        }
    }
    __syncthreads();

    // ---- MFMA screen: 16 waves = 2 seg-blocks x 8 word-groups (4 tiles each) ----
    int w = t >> 6, lane = t & 63;
    {
        int sb = w & 1;        // seg-block: local segments [sb*32, sb*32+32)
        int g = w >> 1;        // word-group (chunk): words [g*128, g*128+128)
        int half = lane >> 5;

        short8v af = {0, 0, 0, 0, 0, 0, 0, 0};
        if (lane < 32) af = segb[sb * 32 + lane];

        float thr_r[16];
#pragma unroll
        for (int i = 0; i < 16; i++) {
            int row = (i & 3) + 8 * (i >> 2) + 4 * half;
            thr_r[i] = thr_l[sb * 32 + row];
        }

        const double MID = 0x1.E66667p-1;
        for (int j = 0; j < 4; j++) {
            int wb = g * 4 + j;
            short8v bf = {0, 0, 0, 0, 0, 0, 0, 0};
            if (lane < 32) bf = wcb_lds[wb * 32 + lane];
            float wsd_c = wsl[wb * 32 + (lane & 31)];

            f32x16 accz = {0.f, 0.f, 0.f, 0.f, 0.f, 0.f, 0.f, 0.f,
                           0.f, 0.f, 0.f, 0.f, 0.f, 0.f, 0.f, 0.f};
            f32x16 acc = __builtin_amdgcn_mfma_f32_32x32x16_bf16(af, bf, accz, 0, 0, 0);

            bool anyp = false;
#pragma unroll
            for (int i = 0; i < 16; i++) anyp |= (fabsf(acc[i]) > thr_r[i] * wsd_c);

            if (__builtin_expect(anyp, 0)) {
#pragma unroll
                for (int i = 0; i < 16; i++) {
                    unsigned long long mi = __ballot(fabsf(acc[i]) > thr_r[i] * wsd_c);
                    while (mi) {
                        int src = __builtin_ctzll(mi);
                        mi &= mi - 1;
                        if (lane == src) {
                            int col = src & 31;
                            int seg_r = sb * 32 + (i & 3) + 8 * (i >> 2) + 4 * (src >> 5); // local
                            int v = wb * 32 + col;
                            float sst = sstd_l[seg_r];
                            float wsd = wsl[v];
                            const float* sc = &segf[seg_r * 8];
                            float4 wa = wcl4[v * 2];
                            float4 wbv = wcl4[v * 2 + 1];
                            // EXACT mul/fma order of previous rounds
                            float dot = sc[0] * wa.x + sc[1] * wa.y + sc[2] * wa.z + sc[3] * wa.w
                                      + sc[4] * wbv.x + sc[5] * wbv.y + sc[6] * wbv.z + sc[7] * wbv.w;
                            float cov = dot * 0.125f;
                            float denom = wsd * sst;
                            if ((double)fabsf(cov) >= MID * (double)denom) {
                                float c = (denom == 0.f) ? 0.f : cov / denom;
                                float a = fabsf(c);
                                int sidx = g * 64 + seg_r;
                                stm[sidx] = fmaxf(stm[sidx], a);
                                if (a > THRESH_ && stb[sidx] < a) { stb[sidx] = c; sti[sidx] = v; }
                            }
                        }
                    }
                }
            }
        }
    }
    __syncthreads();

    // ---- haar sum tree (full row) ----
    if (t < 64) tree[128 + t] = tree[2 * t] + tree[2 * t + 1];
    __syncthreads();
    if (t < 32) tree[192 + t] = tree[128 + 2 * t] + tree[128 + 2 * t + 1];
    __syncthreads();
    if (t < 16) tree[224 + t] = tree[192 + 2 * t] + tree[192 + 2 * t + 1];
    __syncthreads();
    if (t < 8) tree[240 + t] = tree[224 + 2 * t] + tree[224 + 2 * t + 1];
    __syncthreads();
    if (t < 4) tree[248 + t] = tree[240 + 2 * t] + tree[240 + 2 * t + 1];
    __syncthreads();
    if (t < 2) tree[252 + t] = tree[248 + 2 * t] + tree[248 + 2 * t + 1];
    __syncthreads();

    // ---- ordered 8-chunk merge + haar coefficients (t < 64, local rows) ----
    if (t < 64) {
        float Bb = stb[t];
        int I = sti[t];
#pragma unroll
        for (int p = 1; p < 8; p++) {
            float yb = stb[p * 64 + t];
            int yi = sti[p * 64 + t];
            float ym = stm[p * 64 + t];
            bool take = (yi != -1) && (!(Bb > THRESH_) || (ym > Bb));
            if (take) { Bb = yb; I = yi; }
        }
        float mask = (I >= 0) ? 1.f : 0.f;

        int sg = h * 64 + t;   // global segment index
        const int base[7] = {252, 248, 240, 224, 192, 128, 0};
        const float scl[7] = {0.03125f, 0.04419417382415922f, 0.0625f,
                              0.08838834764831843f, 0.125f,
                              0.17677669529663687f, 0.25f};
        float hcv[8];
#pragma unroll
        for (int l = 0; l < 7; l++) {
            int j = (sg << l) >> 7;
            hcv[l] = scl[l] * (tree[base[l] + 2 * j] - tree[base[l] + 2 * j + 1]);
        }
        float s4a = xrow[sg * 8 + 0] + xrow[sg * 8 + 1] + xrow[sg * 8 + 2] + xrow[sg * 8 + 3];
        float s4b = xrow[sg * 8 + 4] + xrow[sg * 8 + 5] + xrow[sg * 8 + 6] + xrow[sg * 8 + 7];
        hcv[7] = 0.3535533905932738f * (s4a - s4b);

#pragma unroll
        for (int l = 0; l < 8; l++) hc_lds[t * 8 + l] = hcv[l] * mask;
        idx_lds[t] = I;
    }
    __syncthreads();

    // ---- phase 2: output assembly for our 64 rows (12 waves x 16 rows) ----
    if (w < 12) {
        int third = w % 3;
        int grp = w / 3;           // 0..3 -> 16 local rows each
        int c = third * 64 + lane;

        float4 he[8];
        const float4* hg = (const float4*)haar_emb;
#pragma unroll
        for (int l = 0; l < 8; l++) he[l] = hg[l * 192 + c];

        const float4* pos4 = (const float4*)pos_emb;
        const float4* we4 = (const float4*)word_emb;
        float4* out4 = (float4*)out + ((size_t)b * 128 + h * 64) * 192;

        for (int k = 0; k < 16; k += 2) {
            int row0 = grp * 16 + k;   // local row
            int row1 = row0 + 1;
            int iv0 = idx_lds[row0];
            int iv1 = idx_lds[row1];
            int ivc0 = iv0 < 0 ? 0 : iv0;
            int ivc1 = iv1 < 0 ? 0 : iv1;
            float msk0 = iv0 < 0 ? 0.f : 1.f;
            float msk1 = iv1 < 0 ? 0.f : 1.f;
            int sg0 = h * 64 + row0, sg1 = h * 64 + row1;
            float4 p0 = pos4[sg0 * 192 + c];
            float4 w0 = we4[(size_t)ivc0 * 192 + c];
            float4 h0a = *(const float4*)&hc_lds[row0 * 8];
            float4 h0b = *(const float4*)&hc_lds[row0 * 8 + 4];
            float4 p1 = pos4[sg1 * 192 + c];
            float4 w1 = we4[(size_t)ivc1 * 192 + c];
            float4 h1a = *(const float4*)&hc_lds[row1 * 8];
            float4 h1b = *(const float4*)&hc_lds[row1 * 8 + 4];

            float4 acc0;
            acc0.x = fmaf(w0.x, msk0, p0.x);
            acc0.y = fmaf(w0.y, msk0, p0.y);
            acc0.z = fmaf(w0.z, msk0, p0.z);
            acc0.w = fmaf(w0.w, msk0, p0.w);
            float h0[8] = {h0a.x, h0a.y, h0a.z, h0a.w, h0b.x, h0b.y, h0b.z, h0b.w};
#pragma unroll
            for (int l = 0; l < 8; l++) {
                acc0.x += h0[l] * he[l].x;
                acc0.y += h0[l] * he[l].y;
                acc0.z += h0[l] * he[l].z;
                acc0.w += h0[l] * he[l].w;
            }
            {
                nfloat4 nv = {acc0.x, acc0.y, acc0.z, acc0.w};
                __builtin_nontemporal_store(nv, (nfloat4*)&out4[row0 * 192 + c]);
            }

            float4 acc1;
            acc1.x = fmaf(w1.x, msk1, p1.x);
            acc1.y = fmaf(w1.y, msk1, p1.y);
            acc1.z = fmaf(w1.z, msk1, p1.z);
            acc1.w = fmaf(w1.w, msk1, p1.w);
            float h1[8] = {h1a.x, h1a.y, h1a.z, h1a.w, h1b.x, h1b.y, h1b.z, h1b.w};
#pragma unroll
            for (int l = 0; l < 8; l++) {
                acc1.x += h1[l] * he[l].x;
                acc1.y += h1[l] * he[l].y;
                acc1.z += h1[l] * he[l].z;
                acc1.w += h1[l] * he[l].w;
            }
            {
                nfloat4 nv = {acc1.x, acc1.y, acc1.z, acc1.w};
                __builtin_nontemporal_store(nv, (nfloat4*)&out4[row1 * 192 + c]);
            }
        }
    }
}

extern "C" void kernel_launch(void* const* d_in, const int* in_sizes, int n_in,
                              void* d_out, int out_size, void* d_ws, size_t ws_size,
                              hipStream_t stream) {
    const float* X        = (const float*)d_in[0];
    const float* vocab    = (const float*)d_in[1];
    const float* word_emb = (const float*)d_in[2];
    const float* haar_emb = (const float*)d_in[3];
    const float* pos_emb  = (const float*)d_in[4];
    float* out = (float*)d_out;

    hipLaunchKernelGGL(k12_fused, dim3(512), dim3(1024), 0, stream,
                       X, vocab, word_emb, haar_emb, pos_emb, out);
}

// Round 13
// 40.951 us; speedup vs baseline: 1.8387x; 1.8387x over previous
//
#include <hip/hip_runtime.h>
#include <math.h>

#define THRESH_ 0.95f

typedef __attribute__((ext_vector_type(8))) short short8v;
typedef __attribute__((ext_vector_type(16))) float f32x16;

__device__ __forceinline__ unsigned short f2bf_rne(float x) {
    unsigned u = __float_as_uint(x);
    u += 0x7fffu + ((u >> 16) & 1u);
    return (unsigned short)(u >> 16);
}

// Fused kernel: one block per batch row (grid 256), 512 threads (8 waves),
// LDS ~74.5 KB => 2 blocks co-resident per CU: one block's staging/select
// overlaps the other block's store drain. Global traffic shape identical to
// the proven R10 kernel (same per-row read/write streams).
__global__ __launch_bounds__(512, 4) void k12_fused(const float* __restrict__ X,
                                                    const float* __restrict__ vocab,
                                                    const float* __restrict__ word_emb,
                                                    const float* __restrict__ haar_emb,
                                                    const float* __restrict__ pos_emb,
                                                    float* __restrict__ out) {
    __shared__ float4  wcl4[2048];    // fp32 centered vocab (32 KB)
    __shared__ short8v wcb_lds[1024]; // bf16 vocab (16 KB)
    __shared__ float   wsl[1024];     // word stds (4 KB)
    __shared__ float   xrow[1024];    // 4 KB
    __shared__ float   segf[1024];    // fp32 centered segments [128][8] (4 KB)
    __shared__ short8v segb[128];     // bf16 segments (2 KB)
    __shared__ float   sstd_l[128];
    __shared__ float   thr_l[128];    // 7.52f * sstd
    __shared__ float   stb[512];      // [4 chunks][128 segs]
    __shared__ int     sti[512];
    __shared__ float   stm[512];
    __shared__ float   tree[254];
    __shared__ float   hc_lds[1024];  // [128][8]
    __shared__ int     idx_lds[128];

    int t = threadIdx.x;
    int b = blockIdx.x;

    // ---- staging: X row + per-word vocab stats (2 words/thread; identical arithmetic) ----
    xrow[t] = X[b * 1024 + t];
    xrow[t + 512] = X[b * 1024 + t + 512];
#pragma unroll
    for (int rep = 0; rep < 2; rep++) {
        int v = t + rep * 512;
        const float4* v4 = (const float4*)vocab + v * 2;
        float4 a = v4[0], bb = v4[1];
        float w[8] = {a.x, a.y, a.z, a.w, bb.x, bb.y, bb.z, bb.w};
        float s = 0.f;
#pragma unroll
        for (int c = 0; c < 8; c++) s += w[c];
        float mean = s * 0.125f;
        float ss = 0.f;
        float wcv[8];
#pragma unroll
        for (int c = 0; c < 8; c++) { wcv[c] = w[c] - mean; ss += wcv[c] * wcv[c]; }
        float sd = sqrtf(ss * 0.125f);
        float4 o0 = {wcv[0], wcv[1], wcv[2], wcv[3]};
        float4 o1 = {wcv[4], wcv[5], wcv[6], wcv[7]};
        wcl4[v * 2] = o0;
        wcl4[v * 2 + 1] = o1;
        wsl[v] = sd;
        union { uint4 q; unsigned short u[8]; } pk;
#pragma unroll
        for (int c = 0; c < 8; c++) pk.u[c] = f2bf_rne(wcv[c]);
        ((uint4*)wcb_lds)[v] = pk.q;
    }
    { stb[t] = -INFINITY; sti[t] = -1; stm[t] = 0.f; }
    __syncthreads();

    // ---- segment stats (t < 128) ----
    if (t < 128) {
        float seg[8];
#pragma unroll
        for (int c = 0; c < 8; c++) seg[c] = xrow[t * 8 + c];
        float sum = 0.f;
#pragma unroll
        for (int c = 0; c < 8; c++) sum += seg[c];
        float mean = sum * 0.125f;
        float segc[8];
        float ss = 0.f;
#pragma unroll
        for (int c = 0; c < 8; c++) { segc[c] = seg[c] - mean; ss += segc[c] * segc[c]; }
        float sstd = sqrtf(ss * 0.125f);
        union { short8v v; unsigned short u[8]; } pk;
#pragma unroll
        for (int c = 0; c < 8; c++) { segf[t * 8 + c] = segc[c]; pk.u[c] = f2bf_rne(segc[c]); }
        segb[t] = pk.v;
        sstd_l[t] = sstd;
        thr_l[t] = 7.52f * sstd;
        tree[t] = sum;
    }
    __syncthreads();

    // ---- MFMA screen: 8 waves = 4 seg-blocks x 2 chunk-pairs; 16 tiles/wave ----
    // Screen |acc_bf16| > 7.52*sstd*wsd: no false negatives vs the exact
    // condition |dot| >= 7.6000000238*RN(wsd*sstd) (bf16 error <= 0.032*sstd*wsd).
    // Rare candidates: exact fp32 dot (same op order) + f64 MID + IEEE divide,
    // v-ascending per (chunk, segment) -> same proven ordered merge.
    int w = t >> 6, lane = t & 63;
    {
        int sb = w & 3;        // seg-block (32 segments)
        int gp = w >> 2;       // chunk-pair: chunks {gp*2, gp*2+1}
        int half = lane >> 5;

        short8v af = {0, 0, 0, 0, 0, 0, 0, 0};
        if (lane < 32) af = segb[sb * 32 + lane];

        float thr_r[16];
#pragma unroll
        for (int i = 0; i < 16; i++) {
            int row = (i & 3) + 8 * (i >> 2) + 4 * half;
            thr_r[i] = thr_l[sb * 32 + row];
        }

        const double MID = 0x1.E66667p-1;
        for (int gg = 0; gg < 2; gg++) {
            int g = gp * 2 + gg;   // chunk: words [g*256, g*256+256)
            for (int j = 0; j < 8; j++) {
                int wb = g * 8 + j;
                short8v bf = {0, 0, 0, 0, 0, 0, 0, 0};
                if (lane < 32) bf = wcb_lds[wb * 32 + lane];
                float wsd_c = wsl[wb * 32 + (lane & 31)];

                f32x16 accz = {0.f, 0.f, 0.f, 0.f, 0.f, 0.f, 0.f, 0.f,
                               0.f, 0.f, 0.f, 0.f, 0.f, 0.f, 0.f, 0.f};
                f32x16 acc = __builtin_amdgcn_mfma_f32_32x32x16_bf16(af, bf, accz, 0, 0, 0);

                bool anyp = false;
#pragma unroll
                for (int i = 0; i < 16; i++) anyp |= (fabsf(acc[i]) > thr_r[i] * wsd_c);

                if (__builtin_expect(anyp, 0)) {
#pragma unroll
                    for (int i = 0; i < 16; i++) {
                        unsigned long long mi = __ballot(fabsf(acc[i]) > thr_r[i] * wsd_c);
                        while (mi) {
                            int src = __builtin_ctzll(mi);
                            mi &= mi - 1;
                            if (lane == src) {
                                int col = src & 31;
                                int seg_r = sb * 32 + (i & 3) + 8 * (i >> 2) + 4 * (src >> 5);
                                int v = wb * 32 + col;
                                float sst = sstd_l[seg_r];
                                float wsd = wsl[v];
                                const float* sc = &segf[seg_r * 8];
                                float4 wa = wcl4[v * 2];
                                float4 wbv = wcl4[v * 2 + 1];
                                // EXACT mul/fma order of previous rounds
                                float dot = sc[0] * wa.x + sc[1] * wa.y + sc[2] * wa.z + sc[3] * wa.w
                                          + sc[4] * wbv.x + sc[5] * wbv.y + sc[6] * wbv.z + sc[7] * wbv.w;
                                float cov = dot * 0.125f;
                                float denom = wsd * sst;
                                if ((double)fabsf(cov) >= MID * (double)denom) {
                                    float c = (denom == 0.f) ? 0.f : cov / denom;
                                    float a = fabsf(c);
                                    int sidx = g * 128 + seg_r;
                                    stm[sidx] = fmaxf(stm[sidx], a);
                                    if (a > THRESH_ && stb[sidx] < a) { stb[sidx] = c; sti[sidx] = v; }
                                }
                            }
                        }
                    }
                }
            }
        }
    }
    __syncthreads();

    // ---- haar sum tree ----
    if (t < 64) tree[128 + t] = tree[2 * t] + tree[2 * t + 1];
    __syncthreads();
    if (t < 32) tree[192 + t] = tree[128 + 2 * t] + tree[128 + 2 * t + 1];
    __syncthreads();
    if (t < 16) tree[224 + t] = tree[192 + 2 * t] + tree[192 + 2 * t + 1];
    __syncthreads();
    if (t < 8) tree[240 + t] = tree[224 + 2 * t] + tree[224 + 2 * t + 1];
    __syncthreads();
    if (t < 4) tree[248 + t] = tree[240 + 2 * t] + tree[240 + 2 * t + 1];
    __syncthreads();
    if (t < 2) tree[252 + t] = tree[248 + 2 * t] + tree[248 + 2 * t + 1];
    __syncthreads();

    // ---- ordered 4-chunk merge + haar coefficients (t < 128) ----
    if (t < 128) {
        float Bb = stb[t];
        int I = sti[t];
#pragma unroll
        for (int p = 1; p < 4; p++) {
            float yb = stb[p * 128 + t];
            int yi = sti[p * 128 + t];
            float ym = stm[p * 128 + t];
            bool take = (yi != -1) && (!(Bb > THRESH_) || (ym > Bb));
            if (take) { Bb = yb; I = yi; }
        }
        float mask = (I >= 0) ? 1.f : 0.f;

        const int base[7] = {252, 248, 240, 224, 192, 128, 0};
        const float scl[7] = {0.03125f, 0.04419417382415922f, 0.0625f,
                              0.08838834764831843f, 0.125f,
                              0.17677669529663687f, 0.25f};
        float hcv[8];
#pragma unroll
        for (int l = 0; l < 7; l++) {
            int j = (t << l) >> 7;
            hcv[l] = scl[l] * (tree[base[l] + 2 * j] - tree[base[l] + 2 * j + 1]);
        }
        float s4a = xrow[t * 8 + 0] + xrow[t * 8 + 1] + xrow[t * 8 + 2] + xrow[t * 8 + 3];
        float s4b = xrow[t * 8 + 4] + xrow[t * 8 + 5] + xrow[t * 8 + 6] + xrow[t * 8 + 7];
        hcv[7] = 0.3535533905932738f * (s4a - s4b);

#pragma unroll
        for (int l = 0; l < 8; l++) hc_lds[t * 8 + l] = hcv[l] * mask;
        idx_lds[t] = I;
    }
    __syncthreads();

    // ---- phase 2: 8 waves x 16 rows x 3 thirds; plain stores ----
    {
        const float4* pos4 = (const float4*)pos_emb;
        const float4* we4 = (const float4*)word_emb;
        const float4* hg = (const float4*)haar_emb;
        float4* out4 = (float4*)out + (size_t)b * 128 * 192;

        for (int k = 0; k < 16; k++) {
            int row = w * 16 + k;
            int iv = idx_lds[row];
            int ivc = iv < 0 ? 0 : iv;
            float msk = iv < 0 ? 0.f : 1.f;
            float4 ha = *(const float4*)&hc_lds[row * 8];
            float4 hb = *(const float4*)&hc_lds[row * 8 + 4];
            float h[8] = {ha.x, ha.y, ha.z, ha.w, hb.x, hb.y, hb.z, hb.w};

            // issue all global loads for the row first
            float4 p0 = pos4[row * 192 + lane];
            float4 p1 = pos4[row * 192 + 64 + lane];
            float4 p2 = pos4[row * 192 + 128 + lane];
            float4 w0 = we4[(size_t)ivc * 192 + lane];
            float4 w1 = we4[(size_t)ivc * 192 + 64 + lane];
            float4 w2 = we4[(size_t)ivc * 192 + 128 + lane];

#pragma unroll
            for (int third = 0; third < 3; third++) {
                int c = third * 64 + lane;
                float4 p = third == 0 ? p0 : (third == 1 ? p1 : p2);
                float4 wv = third == 0 ? w0 : (third == 1 ? w1 : w2);
                float4 acc;
                acc.x = fmaf(wv.x, msk, p.x);
                acc.y = fmaf(wv.y, msk, p.y);
                acc.z = fmaf(wv.z, msk, p.z);
                acc.w = fmaf(wv.w, msk, p.w);
#pragma unroll
                for (int l = 0; l < 8; l++) {
                    float4 he = hg[l * 192 + c];
                    acc.x += h[l] * he.x;
                    acc.y += h[l] * he.y;
                    acc.z += h[l] * he.z;
                    acc.w += h[l] * he.w;
                }
                out4[row * 192 + c] = acc;
            }
        }
    }
}

extern "C" void kernel_launch(void* const* d_in, const int* in_sizes, int n_in,
                              void* d_out, int out_size, void* d_ws, size_t ws_size,
                              hipStream_t stream) {
    const float* X        = (const float*)d_in[0];
    const float* vocab    = (const float*)d_in[1];
    const float* word_emb = (const float*)d_in[2];
    const float* haar_emb = (const float*)d_in[3];
    const float* pos_emb  = (const float*)d_in[4];
    float* out = (float*)d_out;

    hipLaunchKernelGGL(k12_fused, dim3(256), dim3(512), 0, stream,
                       X, vocab, word_emb, haar_emb, pos_emb, out);
}

// Round 14
// 34.154 us; speedup vs baseline: 2.2047x; 1.1990x over previous
//
#include <hip/hip_runtime.h>
#include <math.h>

#define THRESH_ 0.95f

typedef float nfloat4 __attribute__((ext_vector_type(4)));
typedef __attribute__((ext_vector_type(8))) short short8v;
typedef __attribute__((ext_vector_type(16))) float f32x16;

__device__ __forceinline__ unsigned short f2bf_rne(float x) {
    unsigned u = __float_as_uint(x);
    u += 0x7fffu + ((u >> 16) & 1u);
    return (unsigned short)(u >> 16);
}

// R10 skeleton + intra-block pipelining: select/merge half A, then waves 0-11
// store half A while waves 12-15 select half B; merge B; store half B.
__global__ __launch_bounds__(1024) void k12_fused(const float* __restrict__ X,
                                                  const float* __restrict__ vocab,
                                                  const float* __restrict__ word_emb,
                                                  const float* __restrict__ haar_emb,
                                                  const float* __restrict__ pos_emb,
                                                  float* __restrict__ out) {
    __shared__ float4  wcl4[2048];    // fp32 centered vocab (32 KB)
    __shared__ short8v wcb_lds[1024]; // bf16 vocab (16 KB)
    __shared__ float   wsl[1024];     // word stds (4 KB)
    __shared__ float   xrow[1024];    // 4 KB
    __shared__ float   segf[1024];    // fp32 centered segments [128][8]
    __shared__ short8v segb[128];     // bf16 segments
    __shared__ float   sstd_l[128];
    __shared__ float   thr_l[128];    // 7.52f * sstd
    __shared__ float   stbA[512];     // half A: [8 chunks][64 segs]
    __shared__ int     stiA[512];
    __shared__ float   stmA[512];
    __shared__ float   stbB[128];     // half B: [2 chunks][64 segs]
    __shared__ int     stiB[128];
    __shared__ float   stmB[128];
    __shared__ float   tree[254];
    __shared__ float   hc_lds[1024];  // [128][8]
    __shared__ int     idx_lds[128];

    int t = threadIdx.x;
    int b = blockIdx.x;
    int w = t >> 6, lane = t & 63;

    // ---- staging: X row + per-word vocab stats (identical arithmetic) ----
    xrow[t] = X[b * 1024 + t];
    {
        const float4* v4 = (const float4*)vocab + t * 2;
        float4 a = v4[0], bb = v4[1];
        float wv[8] = {a.x, a.y, a.z, a.w, bb.x, bb.y, bb.z, bb.w};
        float s = 0.f;
#pragma unroll
        for (int c = 0; c < 8; c++) s += wv[c];
        float mean = s * 0.125f;
        float ss = 0.f;
        float wcv[8];
#pragma unroll
        for (int c = 0; c < 8; c++) { wcv[c] = wv[c] - mean; ss += wcv[c] * wcv[c]; }
        float sd = sqrtf(ss * 0.125f);
        float4 o0 = {wcv[0], wcv[1], wcv[2], wcv[3]};
        float4 o1 = {wcv[4], wcv[5], wcv[6], wcv[7]};
        wcl4[t * 2] = o0;
        wcl4[t * 2 + 1] = o1;
        wsl[t] = sd;
        union { uint4 q; unsigned short u[8]; } pk;
#pragma unroll
        for (int c = 0; c < 8; c++) pk.u[c] = f2bf_rne(wcv[c]);
        ((uint4*)wcb_lds)[t] = pk.q;
    }
    if (t < 512) { stbA[t] = -INFINITY; stiA[t] = -1; stmA[t] = 0.f; }
    if (t < 128) { stbB[t] = -INFINITY; stiB[t] = -1; stmB[t] = 0.f; }
    __syncthreads();

    // ---- segment stats for all 128 segments ----
    if (t < 128) {
        float seg[8];
#pragma unroll
        for (int c = 0; c < 8; c++) seg[c] = xrow[t * 8 + c];
        float sum = 0.f;
#pragma unroll
        for (int c = 0; c < 8; c++) sum += seg[c];
        float mean = sum * 0.125f;
        float segc[8];
        float ss = 0.f;
#pragma unroll
        for (int c = 0; c < 8; c++) { segc[c] = seg[c] - mean; ss += segc[c] * segc[c]; }
        float sstd = sqrtf(ss * 0.125f);
        union { short8v v; unsigned short u[8]; } pk;
#pragma unroll
        for (int c = 0; c < 8; c++) { segf[t * 8 + c] = segc[c]; pk.u[c] = f2bf_rne(segc[c]); }
        segb[t] = pk.v;
        sstd_l[t] = sstd;
        thr_l[t] = 7.52f * sstd;
        tree[t] = sum;
    }
    __syncthreads();

    const double MID = 0x1.E66667p-1;

    // ---- select half A (segments 0-63): 16 waves = 2 seg-blocks x 8 chunks(128 words), 4 tiles/wave ----
    {
        int sb = w & 1;          // local seg-block
        int g = w >> 1;          // chunk (128 words)
        int lh = lane >> 5;

        short8v af = {0, 0, 0, 0, 0, 0, 0, 0};
        if (lane < 32) af = segb[sb * 32 + lane];

        float thr_r[16];
#pragma unroll
        for (int i = 0; i < 16; i++) {
            int row = (i & 3) + 8 * (i >> 2) + 4 * lh;
            thr_r[i] = thr_l[sb * 32 + row];
        }

        for (int j = 0; j < 4; j++) {
            int wb = g * 4 + j;
            short8v bf = {0, 0, 0, 0, 0, 0, 0, 0};
            if (lane < 32) bf = wcb_lds[wb * 32 + lane];
            float wsd_c = wsl[wb * 32 + (lane & 31)];

            f32x16 accz = {0.f, 0.f, 0.f, 0.f, 0.f, 0.f, 0.f, 0.f,
                           0.f, 0.f, 0.f, 0.f, 0.f, 0.f, 0.f, 0.f};
            f32x16 acc = __builtin_amdgcn_mfma_f32_32x32x16_bf16(af, bf, accz, 0, 0, 0);

            bool anyp = false;
#pragma unroll
            for (int i = 0; i < 16; i++) anyp |= (fabsf(acc[i]) > thr_r[i] * wsd_c);

            if (__builtin_expect(anyp, 0)) {
#pragma unroll
                for (int i = 0; i < 16; i++) {
                    unsigned long long mi = __ballot(fabsf(acc[i]) > thr_r[i] * wsd_c);
                    while (mi) {
                        int src = __builtin_ctzll(mi);
                        mi &= mi - 1;
                        if (lane == src) {
                            int col = src & 31;
                            int seg_l = sb * 32 + (i & 3) + 8 * (i >> 2) + 4 * (src >> 5); // 0..63
                            int v = wb * 32 + col;
                            float sst = sstd_l[seg_l];
                            float wsd = wsl[v];
                            const float* sc = &segf[seg_l * 8];
                            float4 wa = wcl4[v * 2];
                            float4 wbv = wcl4[v * 2 + 1];
                            float dot = sc[0] * wa.x + sc[1] * wa.y + sc[2] * wa.z + sc[3] * wa.w
                                      + sc[4] * wbv.x + sc[5] * wbv.y + sc[6] * wbv.z + sc[7] * wbv.w;
                            float cov = dot * 0.125f;
                            float denom = wsd * sst;
                            if ((double)fabsf(cov) >= MID * (double)denom) {
                                float c = (denom == 0.f) ? 0.f : cov / denom;
                                float a = fabsf(c);
                                int sidx = g * 64 + seg_l;
                                stmA[sidx] = fmaxf(stmA[sidx], a);
                                if (a > THRESH_ && stbA[sidx] < a) { stbA[sidx] = c; stiA[sidx] = v; }
                            }
                        }
                    }
                }
            }
        }
    }
    __syncthreads();

    // ---- haar sum tree ----
    if (t < 64) tree[128 + t] = tree[2 * t] + tree[2 * t + 1];
    __syncthreads();
    if (t < 32) tree[192 + t] = tree[128 + 2 * t] + tree[128 + 2 * t + 1];
    __syncthreads();
    if (t < 16) tree[224 + t] = tree[192 + 2 * t] + tree[192 + 2 * t + 1];
    __syncthreads();
    if (t < 8) tree[240 + t] = tree[224 + 2 * t] + tree[224 + 2 * t + 1];
    __syncthreads();
    if (t < 4) tree[248 + t] = tree[240 + 2 * t] + tree[240 + 2 * t + 1];
    __syncthreads();
    if (t < 2) tree[252 + t] = tree[248 + 2 * t] + tree[248 + 2 * t + 1];
    __syncthreads();

    // ---- merge half A (8 chunks) + haar coeffs rows 0-63 ----
    if (t < 64) {
        float Bb = stbA[t];
        int I = stiA[t];
#pragma unroll
        for (int p = 1; p < 8; p++) {
            float yb = stbA[p * 64 + t];
            int yi = stiA[p * 64 + t];
            float ym = stmA[p * 64 + t];
            bool take = (yi != -1) && (!(Bb > THRESH_) || (ym > Bb));
            if (take) { Bb = yb; I = yi; }
        }
        float mask = (I >= 0) ? 1.f : 0.f;

        int sg = t;  // global segment 0..63
        const int base[7] = {252, 248, 240, 224, 192, 128, 0};
        const float scl[7] = {0.03125f, 0.04419417382415922f, 0.0625f,
                              0.08838834764831843f, 0.125f,
                              0.17677669529663687f, 0.25f};
        float hcv[8];
#pragma unroll
        for (int l = 0; l < 7; l++) {
            int j = (sg << l) >> 7;
            hcv[l] = scl[l] * (tree[base[l] + 2 * j] - tree[base[l] + 2 * j + 1]);
        }
        float s4a = xrow[sg * 8 + 0] + xrow[sg * 8 + 1] + xrow[sg * 8 + 2] + xrow[sg * 8 + 3];
        float s4b = xrow[sg * 8 + 4] + xrow[sg * 8 + 5] + xrow[sg * 8 + 6] + xrow[sg * 8 + 7];
        hcv[7] = 0.3535533905932738f * (s4a - s4b);

#pragma unroll
        for (int l = 0; l < 8; l++) hc_lds[sg * 8 + l] = hcv[l] * mask;
        idx_lds[sg] = I;
    }
    __syncthreads();

    // ---- role phase: waves 0-11 store half A; waves 12-15 select half B ----
    if (w < 12) {
        int third = w % 3;
        int grp = w / 3;           // 0..3 -> rows grp*16 .. +16 (half A)
        int c = third * 64 + lane;

        float4 he[8];
        const float4* hg = (const float4*)haar_emb;
#pragma unroll
        for (int l = 0; l < 8; l++) he[l] = hg[l * 192 + c];

        const float4* pos4 = (const float4*)pos_emb;
        const float4* we4 = (const float4*)word_emb;
        float4* out4 = (float4*)out + (size_t)b * 128 * 192;

        for (int k = 0; k < 16; k++) {
            int row = grp * 16 + k;
            int iv = idx_lds[row];
            int ivc = iv < 0 ? 0 : iv;
            float msk = iv < 0 ? 0.f : 1.f;
            float4 p = pos4[row * 192 + c];
            float4 wv = we4[(size_t)ivc * 192 + c];
            float4 ha = *(const float4*)&hc_lds[row * 8];
            float4 hb = *(const float4*)&hc_lds[row * 8 + 4];
            float h[8] = {ha.x, ha.y, ha.z, ha.w, hb.x, hb.y, hb.z, hb.w};

            float4 acc;
            acc.x = fmaf(wv.x, msk, p.x);
            acc.y = fmaf(wv.y, msk, p.y);
            acc.z = fmaf(wv.z, msk, p.z);
            acc.w = fmaf(wv.w, msk, p.w);
#pragma unroll
            for (int l = 0; l < 8; l++) {
                acc.x += h[l] * he[l].x;
                acc.y += h[l] * he[l].y;
                acc.z += h[l] * he[l].z;
                acc.w += h[l] * he[l].w;
            }
            nfloat4 nv = {acc.x, acc.y, acc.z, acc.w};
            __builtin_nontemporal_store(nv, (nfloat4*)&out4[row * 192 + c]);
        }
    } else {
        // select half B (segments 64-127): 4 waves = 2 seg-blocks x 2 chunks(512 words), 16 tiles/wave
        int wl = w - 12;
        int sb = wl & 1;
        int g = wl >> 1;           // chunk (512 words)
        int lh = lane >> 5;

        short8v af = {0, 0, 0, 0, 0, 0, 0, 0};
        if (lane < 32) af = segb[64 + sb * 32 + lane];

        float thr_r[16];
#pragma unroll
        for (int i = 0; i < 16; i++) {
            int row = (i & 3) + 8 * (i >> 2) + 4 * lh;
            thr_r[i] = thr_l[64 + sb * 32 + row];
        }

        for (int j = 0; j < 16; j++) {
            int wb = g * 16 + j;
            short8v bf = {0, 0, 0, 0, 0, 0, 0, 0};
            if (lane < 32) bf = wcb_lds[wb * 32 + lane];
            float wsd_c = wsl[wb * 32 + (lane & 31)];

            f32x16 accz = {0.f, 0.f, 0.f, 0.f, 0.f, 0.f, 0.f, 0.f,
                           0.f, 0.f, 0.f, 0.f, 0.f, 0.f, 0.f, 0.f};
            f32x16 acc = __builtin_amdgcn_mfma_f32_32x32x16_bf16(af, bf, accz, 0, 0, 0);

            bool anyp = false;
#pragma unroll
            for (int i = 0; i < 16; i++) anyp |= (fabsf(acc[i]) > thr_r[i] * wsd_c);

            if (__builtin_expect(anyp, 0)) {
#pragma unroll
                for (int i = 0; i < 16; i++) {
                    unsigned long long mi = __ballot(fabsf(acc[i]) > thr_r[i] * wsd_c);
                    while (mi) {
                        int src = __builtin_ctzll(mi);
                        mi &= mi - 1;
                        if (lane == src) {
                            int col = src & 31;
                            int seg_l = sb * 32 + (i & 3) + 8 * (i >> 2) + 4 * (src >> 5); // 0..63 local
                            int sg = 64 + seg_l;
                            int v = wb * 32 + col;
                            float sst = sstd_l[sg];
                            float wsd = wsl[v];
                            const float* sc = &segf[sg * 8];
                            float4 wa = wcl4[v * 2];
                            float4 wbv = wcl4[v * 2 + 1];
                            float dot = sc[0] * wa.x + sc[1] * wa.y + sc[2] * wa.z + sc[3] * wa.w
                                      + sc[4] * wbv.x + sc[5] * wbv.y + sc[6] * wbv.z + sc[7] * wbv.w;
                            float cov = dot * 0.125f;
                            float denom = wsd * sst;
                            if ((double)fabsf(cov) >= MID * (double)denom) {
                                float c = (denom == 0.f) ? 0.f : cov / denom;
                                float a = fabsf(c);
                                int sidx = g * 64 + seg_l;
                                stmB[sidx] = fmaxf(stmB[sidx], a);
                                if (a > THRESH_ && stbB[sidx] < a) { stbB[sidx] = c; stiB[sidx] = v; }
                            }
                        }
                    }
                }
            }
        }
    }
    __syncthreads();

    // ---- merge half B (2 chunks) + haar coeffs rows 64-127 ----
    if (t < 64) {
        float Bb = stbB[t];
        int I = stiB[t];
        {
            float yb = stbB[64 + t];
            int yi = stiB[64 + t];
            float ym = stmB[64 + t];
            bool take = (yi != -1) && (!(Bb > THRESH_) || (ym > Bb));
            if (take) { Bb = yb; I = yi; }
        }
        float mask = (I >= 0) ? 1.f : 0.f;

        int sg = 64 + t;
        const int base[7] = {252, 248, 240, 224, 192, 128, 0};
        const float scl[7] = {0.03125f, 0.04419417382415922f, 0.0625f,
                              0.08838834764831843f, 0.125f,
                              0.17677669529663687f, 0.25f};
        float hcv[8];
#pragma unroll
        for (int l = 0; l < 7; l++) {
            int j = (sg << l) >> 7;
            hcv[l] = scl[l] * (tree[base[l] + 2 * j] - tree[base[l] + 2 * j + 1]);
        }
        float s4a = xrow[sg * 8 + 0] + xrow[sg * 8 + 1] + xrow[sg * 8 + 2] + xrow[sg * 8 + 3];
        float s4b = xrow[sg * 8 + 4] + xrow[sg * 8 + 5] + xrow[sg * 8 + 6] + xrow[sg * 8 + 7];
        hcv[7] = 0.3535533905932738f * (s4a - s4b);

#pragma unroll
        for (int l = 0; l < 8; l++) hc_lds[sg * 8 + l] = hcv[l] * mask;
        idx_lds[sg] = I;
    }
    __syncthreads();

    // ---- store half B (waves 0-11) ----
    if (w < 12) {
        int third = w % 3;
        int grp = w / 3;
        int c = third * 64 + lane;

        float4 he[8];
        const float4* hg = (const float4*)haar_emb;
#pragma unroll
        for (int l = 0; l < 8; l++) he[l] = hg[l * 192 + c];

        const float4* pos4 = (const float4*)pos_emb;
        const float4* we4 = (const float4*)word_emb;
        float4* out4 = (float4*)out + (size_t)b * 128 * 192;

        for (int k = 0; k < 16; k++) {
            int row = 64 + grp * 16 + k;
            int iv = idx_lds[row];
            int ivc = iv < 0 ? 0 : iv;
            float msk = iv < 0 ? 0.f : 1.f;
            float4 p = pos4[row * 192 + c];
            float4 wv = we4[(size_t)ivc * 192 + c];
            float4 ha = *(const float4*)&hc_lds[row * 8];
            float4 hb = *(const float4*)&hc_lds[row * 8 + 4];
            float h[8] = {ha.x, ha.y, ha.z, ha.w, hb.x, hb.y, hb.z, hb.w};

            float4 acc;
            acc.x = fmaf(wv.x, msk, p.x);
            acc.y = fmaf(wv.y, msk, p.y);
            acc.z = fmaf(wv.z, msk, p.z);
            acc.w = fmaf(wv.w, msk, p.w);
#pragma unroll
            for (int l = 0; l < 8; l++) {
                acc.x += h[l] * he[l].x;
                acc.y += h[l] * he[l].y;
                acc.z += h[l] * he[l].z;
                acc.w += h[l] * he[l].w;
            }
            nfloat4 nv = {acc.x, acc.y, acc.z, acc.w};
            __builtin_nontemporal_store(nv, (nfloat4*)&out4[row * 192 + c]);
        }
    }
}

extern "C" void kernel_launch(void* const* d_in, const int* in_sizes, int n_in,
                              void* d_out, int out_size, void* d_ws, size_t ws_size,
                              hipStream_t stream) {
    const float* X        = (const float*)d_in[0];
    const float* vocab    = (const float*)d_in[1];
    const float* word_emb = (const float*)d_in[2];
    const float* haar_emb = (const float*)d_in[3];
    const float* pos_emb  = (const float*)d_in[4];
    float* out = (float*)d_out;

    hipLaunchKernelGGL(k12_fused, dim3(256), dim3(1024), 0, stream,
                       X, vocab, word_emb, haar_emb, pos_emb, out);
}